// Round 6
// baseline (185.115 us; speedup 1.0000x reference)
//
#include <hip/hip_runtime.h>

#define HH 160
#define WW 160
#define DD 160
#define BB 4
#define NPB (HH * WW * DD / 4)   // 1,024,000 float4 per batch
#define K1B 256                   // min-pass blocks per batch
#define TPP 6400                  // threads per (b,y) plane in pass A

typedef float vfloat4 __attribute__((ext_vector_type(4)));

// ws layout (bytes):
//   0     : partial[1024]  (float)   block-partial mins
//   4096  : cst[48]        (double)  affine constants
//   4608  : fillv[4]       (float)   final per-batch fill
//   5120  : counter        (uint)    compacted-list length
//   8192  : list[]         (uint)    compacted group ids

// ---- kernel 1: per-batch block-partial min (no atomics) + affine constants ----
//   ix = R00*x + R01*y + R02*z + 79.5*(t0 - R00 - R01 - R02 + 1)
// (exact fold of linspace + cx scaling, since 79.5*(2/159) == 1).
__global__ __launch_bounds__(256) void min_cst_kernel(const float4* __restrict__ img4,
                                                      const float* __restrict__ transfos,
                                                      float* __restrict__ partial,
                                                      double* __restrict__ cst) {
    const int b = blockIdx.y;
    const size_t base = (size_t)b * NPB;
    const int t0 = blockIdx.x * 256 + threadIdx.x;   // < 65536
    const int S = K1B * 256;                          // 65536

    float m = 3.4e38f;
    #pragma unroll
    for (int r = 0; r < 4; r++) {
        const int i0 = t0 + 4 * r * S;
        float4 v0 = img4[base + i0];
        float4 v1 = img4[base + i0 + S];
        float4 v2 = img4[base + i0 + 2 * S];
        float4 v3 = make_float4(3.4e38f, 3.4e38f, 3.4e38f, 3.4e38f);
        if (i0 + 3 * S < NPB) v3 = img4[base + i0 + 3 * S];   // only r==3 can fail
        m = fminf(m, fminf(fminf(v0.x, v0.y), fminf(v0.z, v0.w)));
        m = fminf(m, fminf(fminf(v1.x, v1.y), fminf(v1.z, v1.w)));
        m = fminf(m, fminf(fminf(v2.x, v2.y), fminf(v2.z, v2.w)));
        m = fminf(m, fminf(fminf(v3.x, v3.y), fminf(v3.z, v3.w)));
    }

    #pragma unroll
    for (int o = 32; o >= 1; o >>= 1) m = fminf(m, __shfl_down(m, o));
    __shared__ float s[4];
    const int lane = threadIdx.x & 63, wid = threadIdx.x >> 6;
    if (lane == 0) s[wid] = m;
    __syncthreads();
    if (threadIdx.x == 0) {
        partial[b * K1B + blockIdx.x] =
            fminf(fminf(s[0], s[1]), fminf(s[2], s[3]));
    }

    // affine constants (fp64), once per batch, by block (0,0) threads 0..3
    if (blockIdx.x == 0 && blockIdx.y == 0 && threadIdx.x < BB) {
        const int bb = threadIdx.x;
        const float* q = transfos + bb * 7;
        double x = q[0], y = q[1], z = q[2], w = q[3];
        double tx = 2.0 * x, ty = 2.0 * y, tz = 2.0 * z;
        double twx = tx * w, twy = ty * w, twz = tz * w;
        double txx = tx * x, txy = ty * x, txz = tz * x;
        double tyy = ty * y, tyz = tz * y, tzz = tz * z;
        double R[3][3] = {
            {1.0 - (tyy + tzz), txy - twz,         txz + twy},
            {txy + twz,         1.0 - (txx + tzz), tyz - twx},
            {txz - twy,         tyz + twx,         1.0 - (txx + tyy)}
        };
        double t[3] = {(double)q[4], (double)q[5], (double)q[6]};
        for (int r = 0; r < 3; r++) {
            cst[bb * 12 + r * 4 + 0] = R[r][0];
            cst[bb * 12 + r * 4 + 1] = R[r][1];
            cst[bb * 12 + r * 4 + 2] = R[r][2];
            cst[bb * 12 + r * 4 + 3] = 79.5 * (t[r] - R[r][0] - R[r][1] - R[r][2] + 1.0);
        }
    }
}

// ---- pass A: write fill everywhere + compact valid group ids ----
// grid (25, 160, 4) x 256. thread t in [0,6400): x = t/40, zq = (t%40)*4.
// group id g = (b*160 + y)*6400 + t.
__global__ __launch_bounds__(256) void fill_compact_kernel(const double* __restrict__ cst,
                                                           const float* __restrict__ partial,
                                                           float* __restrict__ fillv,
                                                           unsigned* __restrict__ counter,
                                                           unsigned* __restrict__ list,
                                                           unsigned cap,
                                                           float* __restrict__ out) {
    const int b = blockIdx.z;
    const int y = blockIdx.y;

    // ---- fill = min over this batch's 256 partials ----
    __shared__ float sred[4];
    float pm = partial[b * K1B + threadIdx.x];
    #pragma unroll
    for (int o = 32; o >= 1; o >>= 1) pm = fminf(pm, __shfl_down(pm, o));
    if ((threadIdx.x & 63) == 0) sred[threadIdx.x >> 6] = pm;
    __syncthreads();
    const float fill = fminf(fminf(sred[0], sred[1]), fminf(sred[2], sred[3]));
    if (blockIdx.x == 0 && blockIdx.y == 0 && threadIdx.x == 0) fillv[b] = fill;

    const int t = blockIdx.x * 256 + threadIdx.x;   // [0, 6400)
    const int x = t / 40;
    const int zq = (t - 40 * x) * 4;

    const double* c = cst + b * 12;
    const double c2 = c[2], c6 = c[6], c10 = c[10];
    const double dx = (double)x, dy = (double)y, dz = (double)zq;
    double jx = fma(c[0], dx, fma(c[1], dy, fma(c2, dz, c[3])));
    double jy = fma(c[4], dx, fma(c[5], dy, fma(c6, dz, c[7])));
    double jz = fma(c[8], dx, fma(c[9], dy, fma(c10, dz, c[11])));

    bool has = false;
    #pragma unroll
    for (int k = 0; k < 4; k++) {
        has |= (jx >= 0.0) && (jx <= 159.0) && (jy >= 0.0) && (jy <= 159.0) &&
               (jz >= 0.0) && (jz <= 159.0);
        jx += c2; jy += c6; jz += c10;
    }

    // fill everywhere; pass B overwrites the valid groups
    vfloat4 r = {fill, fill, fill, fill};
    vfloat4* outp = (vfloat4*)(out + (size_t)(b * HH + y) * (WW * DD) + x * DD + zq);
    __builtin_nontemporal_store(r, outp);

    // wave-aggregated append of group ids
    unsigned long long mask = __ballot(has);
    if (mask != 0ull) {
        const int lane = threadIdx.x & 63;
        const int leader = __ffsll((long long)mask) - 1;
        unsigned base = 0;
        if (lane == leader) base = atomicAdd(counter, (unsigned)__popcll(mask));
        base = __shfl(base, leader);
        if (has) {
            unsigned idx = base + __popcll(mask & ((1ull << lane) - 1ull));
            if (idx < cap) list[idx] = (unsigned)((b * HH + y) * TPP + t);
        }
    }
}

// ---- pass B: gather + trilinear for compacted groups only ----
// Every lane handles one group (4 voxels, up to 32 loads, single exec region).
__global__ __launch_bounds__(256) void gather_kernel(const float* __restrict__ img,
                                                     const double* __restrict__ cst,
                                                     const float* __restrict__ fillv,
                                                     const unsigned* __restrict__ counter,
                                                     const unsigned* __restrict__ list,
                                                     unsigned cap,
                                                     float* __restrict__ out) {
    unsigned n = *counter;
    if (n > cap) n = cap;
    for (unsigned i = blockIdx.x * 256 + threadIdx.x; i < n; i += gridDim.x * 256) {
        const unsigned g = list[i];
        const int t = g % TPP;
        const unsigned q = g / TPP;
        const int y = q % HH;
        const int b = q / HH;
        const int x = t / 40;
        const int zq = (t - 40 * x) * 4;

        const double* c = cst + b * 12;
        const double c2 = c[2], c6 = c[6], c10 = c[10];
        const double dx = (double)x, dy = (double)y, dz = (double)zq;
        double jx = fma(c[0], dx, fma(c[1], dy, fma(c2, dz, c[3])));
        double jy = fma(c[4], dx, fma(c[5], dy, fma(c6, dz, c[7])));
        double jz = fma(c[8], dx, fma(c[9], dy, fma(c10, dz, c[11])));

        const float fill = fillv[b];
        const float* base = img + (size_t)b * (HH * WW * DD);

        bool vld[4];
        float v[4][8];
        float fx[4], fy[4], fz[4];
        #pragma unroll
        for (int k = 0; k < 4; k++) {
            vld[k] = (jx >= 0.0) && (jx <= 159.0) && (jy >= 0.0) && (jy <= 159.0) &&
                     (jz >= 0.0) && (jz <= 159.0);
            // clamp: identity for valid k, in-bounds-safe for invalid ones
            double cx = fmin(fmax(jx, 0.0), 159.0);
            double cy = fmin(fmax(jy, 0.0), 159.0);
            double cz = fmin(fmax(jz, 0.0), 159.0);
            double flx = floor(cx), fly = floor(cy), flz = floor(cz);
            int x0 = (int)flx, y0 = (int)fly, z0 = (int)flz;
            fx[k] = (float)(cx - flx); fy[k] = (float)(cy - fly); fz[k] = (float)(cz - flz);
            int x1 = min(x0 + 1, 159), y1 = min(y0 + 1, 159), z1 = min(z0 + 1, 159);
            const float* p00 = base + ((size_t)y0 * WW + x0) * DD;  // (y0, x0)
            const float* p01 = base + ((size_t)y0 * WW + x1) * DD;  // (y0, x1)
            const float* p10 = base + ((size_t)y1 * WW + x0) * DD;  // (y1, x0)
            const float* p11 = base + ((size_t)y1 * WW + x1) * DD;  // (y1, x1)
            v[k][0] = p00[z0]; v[k][1] = p00[z1];   // (ox=0, oy=0)
            v[k][2] = p10[z0]; v[k][3] = p10[z1];   // (ox=0, oy=1)
            v[k][4] = p01[z0]; v[k][5] = p01[z1];   // (ox=1, oy=0)
            v[k][6] = p11[z0]; v[k][7] = p11[z1];   // (ox=1, oy=1)
            jx += c2; jy += c6; jz += c10;
        }

        vfloat4 r;
        #pragma unroll
        for (int k = 0; k < 4; k++) {
            float wx0 = 1.0f - fx[k], wx1 = fx[k];
            float wy0 = 1.0f - fy[k], wy1 = fy[k];
            float wz0 = 1.0f - fz[k], wz1 = fz[k];
            // accumulate in the reference's (ox,oy,oz) order
            float a;
            a  = ((wx0 * wy0) * wz0) * v[k][0];
            a += ((wx0 * wy0) * wz1) * v[k][1];
            a += ((wx0 * wy1) * wz0) * v[k][2];
            a += ((wx0 * wy1) * wz1) * v[k][3];
            a += ((wx1 * wy0) * wz0) * v[k][4];
            a += ((wx1 * wy0) * wz1) * v[k][5];
            a += ((wx1 * wy1) * wz0) * v[k][6];
            a += ((wx1 * wy1) * wz1) * v[k][7];
            r[k] = vld[k] ? a : fill;
        }

        vfloat4* outp = (vfloat4*)(out + (size_t)q * (WW * DD) + x * DD + zq);
        *outp = r;
    }
}

extern "C" void kernel_launch(void* const* d_in, const int* in_sizes, int n_in,
                              void* d_out, int out_size, void* d_ws, size_t ws_size,
                              hipStream_t stream) {
    const float* img = (const float*)d_in[0];
    const float* transfos = (const float*)d_in[1];
    float* out = (float*)d_out;
    char* ws = (char*)d_ws;
    float* partial = (float*)ws;
    double* cst = (double*)(ws + 4096);
    float* fillv = (float*)(ws + 4608);
    unsigned* counter = (unsigned*)(ws + 5120);
    unsigned* list = (unsigned*)(ws + 8192);
    unsigned cap = (unsigned)((ws_size > 8192) ? (ws_size - 8192) / 4 : 0);

    (void)hipMemsetAsync(counter, 0, sizeof(unsigned), stream);
    min_cst_kernel<<<dim3(K1B, BB), 256, 0, stream>>>((const float4*)img, transfos,
                                                      partial, cst);
    fill_compact_kernel<<<dim3(25, 160, BB), 256, 0, stream>>>(cst, partial, fillv,
                                                               counter, list, cap, out);
    gather_kernel<<<dim3(1024), 256, 0, stream>>>(img, cst, fillv, counter, list, cap, out);
}

// Round 7
// 136.013 us; speedup vs baseline: 1.3610x; 1.3610x over previous
//
#include <hip/hip_runtime.h>

#define HH 160
#define WW 160
#define DD 160
#define BB 4
#define NPB (HH * WW * DD / 4)   // 1,024,000 float4 per batch
#define K1B 256                   // min-pass blocks per batch

typedef float vfloat4 __attribute__((ext_vector_type(4)));

// ---- monotone float<->uint mapping for atomic min on floats ----
__device__ __forceinline__ unsigned mapf(float f) {
    unsigned b = __float_as_uint(f);
    return (b & 0x80000000u) ? ~b : (b | 0x80000000u);
}
__device__ __forceinline__ float unmapf(unsigned k) {
    unsigned b = (k & 0x80000000u) ? (k ^ 0x80000000u) : ~k;
    return __uint_as_float(b);
}

// ws layout (bytes):
//   0    : minkey[b] at b*256 (uint, one per cache line; init 0xFF by memset)
//   4096 : cst[48] (double)

// ---- kernel 1: per-batch min (atomicMin, line-separated keys) + constants ----
//   ix = R00*x + R01*y + R02*z + 79.5*(t0 - R00 - R01 - R02 + 1)
// (exact fold of linspace + cx scaling, since 79.5*(2/159) == 1).
__global__ __launch_bounds__(256) void min_cst_kernel(const float4* __restrict__ img4,
                                                      const float* __restrict__ transfos,
                                                      unsigned* __restrict__ minkey,
                                                      double* __restrict__ cst) {
    const int b = blockIdx.y;
    const size_t base = (size_t)b * NPB;
    const int t0 = blockIdx.x * 256 + threadIdx.x;   // < 65536
    const int S = K1B * 256;                          // 65536

    float m = 3.4e38f;
    #pragma unroll
    for (int r = 0; r < 4; r++) {
        const int i0 = t0 + 4 * r * S;
        float4 v0 = img4[base + i0];
        float4 v1 = img4[base + i0 + S];
        float4 v2 = img4[base + i0 + 2 * S];
        float4 v3 = make_float4(3.4e38f, 3.4e38f, 3.4e38f, 3.4e38f);
        if (i0 + 3 * S < NPB) v3 = img4[base + i0 + 3 * S];   // only r==3 can fail
        m = fminf(m, fminf(fminf(v0.x, v0.y), fminf(v0.z, v0.w)));
        m = fminf(m, fminf(fminf(v1.x, v1.y), fminf(v1.z, v1.w)));
        m = fminf(m, fminf(fminf(v2.x, v2.y), fminf(v2.z, v2.w)));
        m = fminf(m, fminf(fminf(v3.x, v3.y), fminf(v3.z, v3.w)));
    }

    #pragma unroll
    for (int o = 32; o >= 1; o >>= 1) m = fminf(m, __shfl_down(m, o));
    __shared__ float s[4];
    const int lane = threadIdx.x & 63, wid = threadIdx.x >> 6;
    if (lane == 0) s[wid] = m;
    __syncthreads();
    if (threadIdx.x == 0) {
        m = fminf(fminf(s[0], s[1]), fminf(s[2], s[3]));
        atomicMin(&minkey[b * 64], mapf(m));   // b*64 uints = 256B apart
    }

    // affine constants (fp64), once per batch, by block (0,0) threads 0..3
    if (blockIdx.x == 0 && blockIdx.y == 0 && threadIdx.x < BB) {
        const int bb = threadIdx.x;
        const float* q = transfos + bb * 7;
        double x = q[0], y = q[1], z = q[2], w = q[3];
        double tx = 2.0 * x, ty = 2.0 * y, tz = 2.0 * z;
        double twx = tx * w, twy = ty * w, twz = tz * w;
        double txx = tx * x, txy = ty * x, txz = tz * x;
        double tyy = ty * y, tyz = tz * y, tzz = tz * z;
        double R[3][3] = {
            {1.0 - (tyy + tzz), txy - twz,         txz + twy},
            {txy + twz,         1.0 - (txx + tzz), tyz - twx},
            {txz - twy,         tyz + twx,         1.0 - (txx + tyy)}
        };
        double t[3] = {(double)q[4], (double)q[5], (double)q[6]};
        for (int r = 0; r < 3; r++) {
            cst[bb * 12 + r * 4 + 0] = R[r][0];
            cst[bb * 12 + r * 4 + 1] = R[r][1];
            cst[bb * 12 + r * 4 + 2] = R[r][2];
            cst[bb * 12 + r * 4 + 3] = 79.5 * (t[r] - R[r][0] - R[r][1] - R[r][2] + 1.0);
        }
    }
}

// ---- kernel 2: affine map + trilinear gather, 4 z-outputs per thread ----
// grid (25, 160, 4) x 256. thread t in [0,6400): x = t/40, zq = (t%40)*4.
// Phase split: all addresses unmasked -> 4 masked LOAD-ONLY groups issued
// back-to-back (loads from all k in flight) -> unmasked compute + select.
// Plain (cached) float4 store — NT writes measured ~1 TB/s, plain ~6 TB/s.
__global__ __launch_bounds__(256) void st3d_kernel(const float* __restrict__ img,
                                                   const double* __restrict__ cst,
                                                   const unsigned* __restrict__ minkey,
                                                   float* __restrict__ out) {
    const int b = blockIdx.z;
    const int y = blockIdx.y;
    const float fill = unmapf(minkey[b * 64]);

    const int t = blockIdx.x * 256 + threadIdx.x;   // [0, 6400)
    const int x = t / 40;
    const int zq = (t - 40 * x) * 4;

    const double* c = cst + b * 12;
    const double c2 = c[2], c6 = c[6], c10 = c[10];
    const double dx = (double)x, dy = (double)y, dz = (double)zq;
    double jx = fma(c[0], dx, fma(c[1], dy, fma(c2, dz, c[3])));
    double jy = fma(c[4], dx, fma(c[5], dy, fma(c6, dz, c[7])));
    double jz = fma(c[8], dx, fma(c[9], dy, fma(c10, dz, c[11])));

    const float* base = img + (size_t)b * (HH * WW * DD);

    // ---- phase 0: validity + fracs + line pointers, all lanes (no memory) ----
    bool vld[4];
    float fx[4], fy[4], fz[4];
    const float* pp[4][4];
    int zz0[4], zz1[4];
    #pragma unroll
    for (int k = 0; k < 4; k++) {
        vld[k] = (jx >= 0.0) && (jx <= 159.0) && (jy >= 0.0) && (jy <= 159.0) &&
                 (jz >= 0.0) && (jz <= 159.0);
        double flx = floor(jx), fly = floor(jy), flz = floor(jz);
        int x0 = (int)flx, y0 = (int)fly, z0 = (int)flz;
        fx[k] = (float)(jx - flx); fy[k] = (float)(jy - fly); fz[k] = (float)(jz - flz);
        int x1 = min(x0 + 1, 159), y1 = min(y0 + 1, 159), z1 = min(z0 + 1, 159);
        pp[k][0] = base + ((size_t)y0 * WW + x0) * DD;  // (y0, x0)
        pp[k][1] = base + ((size_t)y1 * WW + x0) * DD;  // (y1, x0)
        pp[k][2] = base + ((size_t)y0 * WW + x1) * DD;  // (y0, x1)
        pp[k][3] = base + ((size_t)y1 * WW + x1) * DD;  // (y1, x1)
        zz0[k] = z0; zz1[k] = z1;
        jx += c2; jy += c6; jz += c10;
    }

    // ---- phase A: masked load-only groups, no use in between ----
    float v[4][8];
    #pragma unroll
    for (int k = 0; k < 4; k++) {
        if (vld[k]) {
            v[k][0] = pp[k][0][zz0[k]]; v[k][1] = pp[k][0][zz1[k]];  // (ox=0, oy=0)
            v[k][2] = pp[k][1][zz0[k]]; v[k][3] = pp[k][1][zz1[k]];  // (ox=0, oy=1)
            v[k][4] = pp[k][2][zz0[k]]; v[k][5] = pp[k][2][zz1[k]];  // (ox=1, oy=0)
            v[k][6] = pp[k][3][zz0[k]]; v[k][7] = pp[k][3][zz1[k]];  // (ox=1, oy=1)
        }
    }

    // ---- phase B: weights in the reference's (ox,oy,oz) order + select ----
    vfloat4 r;
    #pragma unroll
    for (int k = 0; k < 4; k++) {
        float wx0 = 1.0f - fx[k], wx1 = fx[k];
        float wy0 = 1.0f - fy[k], wy1 = fy[k];
        float wz0 = 1.0f - fz[k], wz1 = fz[k];
        float a;
        a  = ((wx0 * wy0) * wz0) * v[k][0];
        a += ((wx0 * wy0) * wz1) * v[k][1];
        a += ((wx0 * wy1) * wz0) * v[k][2];
        a += ((wx0 * wy1) * wz1) * v[k][3];
        a += ((wx1 * wy0) * wz0) * v[k][4];
        a += ((wx1 * wy0) * wz1) * v[k][5];
        a += ((wx1 * wy1) * wz0) * v[k][6];
        a += ((wx1 * wy1) * wz1) * v[k][7];
        r[k] = vld[k] ? a : fill;
    }

    vfloat4* outp = (vfloat4*)(out + (size_t)(b * HH + y) * (WW * DD) + x * DD + zq);
    *outp = r;
}

extern "C" void kernel_launch(void* const* d_in, const int* in_sizes, int n_in,
                              void* d_out, int out_size, void* d_ws, size_t ws_size,
                              hipStream_t stream) {
    const float* img = (const float*)d_in[0];
    const float* transfos = (const float*)d_in[1];
    float* out = (float*)d_out;
    unsigned* minkey = (unsigned*)d_ws;                 // keys at 256B stride
    double* cst = (double*)((char*)d_ws + 4096);

    (void)hipMemsetAsync(minkey, 0xFF, 1024, stream);
    min_cst_kernel<<<dim3(K1B, BB), 256, 0, stream>>>((const float4*)img, transfos,
                                                      minkey, cst);
    st3d_kernel<<<dim3(25, 160, BB), 256, 0, stream>>>(img, cst, minkey, out);
}